// Round 4
// baseline (662.478 us; speedup 1.0000x reference)
//
#include <hip/hip_runtime.h>

#define NODES 100000
#define INDIM 256
#define HDIM 128
#define ODIM 40

typedef short bf16x8 __attribute__((ext_vector_type(8)));   // 8 bf16 (4 VGPR)
typedef float f32x16 __attribute__((ext_vector_type(16)));  // MFMA 32x32 accumulator

// ---------------- CSR build ----------------

__global__ void k_hist(const int* __restrict__ dst, int E, int* __restrict__ counts){
    int e = blockIdx.x * 256 + threadIdx.x;
    if(e < E) atomicAdd(&counts[dst[e]], 1);
}

__global__ void k_psum(const int* __restrict__ counts, int* __restrict__ partial, int n){
    __shared__ int sm[256];
    int chunk = (n + 255) >> 8;
    int start = blockIdx.x * chunk;
    int end = min(start + chunk, n);
    int s = 0;
    for(int i = start + threadIdx.x; i < end; i += 256) s += counts[i];
    sm[threadIdx.x] = s;
    __syncthreads();
    for(int off = 128; off > 0; off >>= 1){
        if(threadIdx.x < off) sm[threadIdx.x] += sm[threadIdx.x + off];
        __syncthreads();
    }
    if(threadIdx.x == 0) partial[blockIdx.x] = sm[0];
}

__global__ void k_scan256(const int* __restrict__ partial, int* __restrict__ pscan){
    __shared__ int sm[256];
    int t = threadIdx.x;
    sm[t] = partial[t];
    __syncthreads();
    for(int off = 1; off < 256; off <<= 1){
        int v = (t >= off) ? sm[t - off] : 0;
        __syncthreads();
        sm[t] += v;
        __syncthreads();
    }
    pscan[t] = (t == 0) ? 0 : sm[t - 1];
}

__global__ void k_scan_final(const int* __restrict__ counts, const int* __restrict__ pscan,
                             int n, int E, int* __restrict__ row_start, int* __restrict__ cursor,
                             float* __restrict__ dinv){
    __shared__ int sm[512];
    int chunk = (n + 255) >> 8;
    int b = blockIdx.x, t = threadIdx.x;
    int idx = b * chunk + t;
    int c = (t < chunk && idx < n) ? counts[idx] : 0;
    sm[t] = c;
    __syncthreads();
    for(int off = 1; off < 512; off <<= 1){
        int v = (t >= off) ? sm[t - off] : 0;
        __syncthreads();
        sm[t] += v;
        __syncthreads();
    }
    if(t < chunk && idx < n){
        int rs = pscan[b] + sm[t] - c;   // exclusive
        row_start[idx] = rs;
        cursor[idx] = rs;
        dinv[idx] = rsqrtf((float)(c + 1));   // +1 self loop
    }
    if(b == 0 && t == 0) row_start[n] = E;
}

__global__ void k_fill(const int* __restrict__ src, const int* __restrict__ dst, int E,
                       int* __restrict__ cursor, int* __restrict__ esrc){
    int e = blockIdx.x * 256 + threadIdx.x;
    if(e < E){
        int p = atomicAdd(&cursor[dst[e]], 1);
        esrc[p] = src[e];
    }
}

// ---------------- W1 split/transpose: [256][128] f32 -> [128][256] bf16 hi/lo ----------------
__global__ void k_wsplit(const float* __restrict__ W, unsigned short* __restrict__ wth,
                         unsigned short* __restrict__ wtl){
    int c = blockIdx.x;      // 0..127 (output col)
    int k = threadIdx.x;     // 0..255
    float f = W[(size_t)k * HDIM + c];
    unsigned u = __float_as_uint(f);
    unsigned short hs = (unsigned short)(u >> 16);            // truncate-split
    float lf = f - __uint_as_float(u & 0xffff0000u);
    unsigned short ls = (unsigned short)(__float_as_uint(lf) >> 16);
    wth[(size_t)c * INDIM + k] = hs;
    wtl[(size_t)c * INDIM + k] = ls;
}

// ---------------- GEMM1 (MFMA split-bf16): h' = dinv .* (x @ W1) ----------------
// One wave = 32 rows x 128 cols. LDS-free: A frags are lane-local f32 loads,
// split in-register; B frags stream from pre-split W1T (L2-resident, 128 KB).
// mfma_f32_32x32x16_bf16: A row=l&31,k=(l>>5)*8+i; B k=(l>>5)*8+i,col=l&31;
// C/D col=l&31, row=(reg&3)+8*(reg>>2)+4*(l>>5)  [m74/m101-verified]
__device__ inline void split8(const float4 v0, const float4 v1, bf16x8& hi, bf16x8& lo){
    const float f[8] = {v0.x, v0.y, v0.z, v0.w, v1.x, v1.y, v1.z, v1.w};
    #pragma unroll
    for(int i = 0; i < 8; ++i){
        unsigned u = __float_as_uint(f[i]);
        hi[i] = (short)(u >> 16);
        float lf = f[i] - __uint_as_float(u & 0xffff0000u);
        lo[i] = (short)(__float_as_uint(lf) >> 16);
    }
}

__global__ __launch_bounds__(256, 3) void k_gemm1(const float* __restrict__ x,
        const unsigned short* __restrict__ wth, const unsigned short* __restrict__ wtl,
        const float* __restrict__ dinv, float* __restrict__ h, int n){
    int wid = blockIdx.x * 4 + (threadIdx.x >> 6);
    if(wid >= (n >> 5)) return;              // 3125 waves, no row tail (100000 = 32*3125)
    int lane = threadIdx.x & 63;
    int r  = lane & 31;                      // A row within tile == B col within colfrag
    int hk = lane >> 5;                      // k-half (0/1)
    int row0 = wid * 32;

    f32x16 acc[4];
    #pragma unroll
    for(int cf = 0; cf < 4; ++cf)
        #pragma unroll
        for(int i = 0; i < 16; ++i) acc[cf][i] = 0.f;

    const float* ap = x + (size_t)(row0 + r) * INDIM + hk * 8;
    const unsigned short* bhp = wth + (size_t)r * INDIM + hk * 8;   // + cf*32*INDIM
    const unsigned short* blp = wtl + (size_t)r * INDIM + hk * 8;

    for(int kk = 0; kk < 16; ++kk){          // K = 256, BK = 16
        int ko = kk * 16;
        float4 a0 = *(const float4*)(ap + ko);
        float4 a1 = *(const float4*)(ap + ko + 4);
        bf16x8 bh[4], bl[4];
        #pragma unroll
        for(int cf = 0; cf < 4; ++cf){
            bh[cf] = *(const bf16x8*)(bhp + (size_t)cf * 32 * INDIM + ko);
            bl[cf] = *(const bf16x8*)(blp + (size_t)cf * 32 * INDIM + ko);
        }
        bf16x8 ah, al;
        split8(a0, a1, ah, al);
        #pragma unroll
        for(int cf = 0; cf < 4; ++cf){
            acc[cf] = __builtin_amdgcn_mfma_f32_32x32x16_bf16(ah, bh[cf], acc[cf], 0, 0, 0);
            acc[cf] = __builtin_amdgcn_mfma_f32_32x32x16_bf16(ah, bl[cf], acc[cf], 0, 0, 0);
            acc[cf] = __builtin_amdgcn_mfma_f32_32x32x16_bf16(al, bh[cf], acc[cf], 0, 0, 0);
        }
    }

    // epilogue: scale by dinv[row], store f32
    #pragma unroll
    for(int reg = 0; reg < 16; ++reg){
        int row = row0 + (reg & 3) + 8 * (reg >> 2) + 4 * hk;
        float di = dinv[row];
        float* hp = h + (size_t)row * HDIM + r;
        #pragma unroll
        for(int cf = 0; cf < 4; ++cf)
            hp[cf * 32] = acc[cf][reg] * di;
    }
}

// ---------------- GEMM2: h' = dinv .* (a @ W2), [N,128]@[128,40] ----------------
__global__ __launch_bounds__(256) void k_gemm2(const float* __restrict__ a, const float* __restrict__ W,
                                               const float* __restrict__ dinv,
                                               float* __restrict__ h, int n){
    __shared__ float xs[64][132];
    __shared__ float ws[HDIM][ODIM];
    int tid = threadIdx.x;
    int row0 = blockIdx.x * 64;
    #pragma unroll
    for(int jj = 0; jj < 8; ++jj){
        int f = tid + 256 * jj;       // float4 index, 2048 total
        int r = f >> 5;
        int c4 = (f & 31) << 2;
        float4 v = make_float4(0.f, 0.f, 0.f, 0.f);
        int grow = row0 + r;
        if(grow < n) v = *(const float4*)&a[(size_t)grow * HDIM + c4];
        *(float4*)&xs[r][c4] = v;
    }
    #pragma unroll
    for(int jj = 0; jj < 5; ++jj){
        int f = tid + 256 * jj;       // 1280 float4 exact
        int r = f / 10;
        int c4 = (f % 10) << 2;
        *(float4*)&ws[r][c4] = *(const float4*)&W[(size_t)r * ODIM + c4];
    }
    __syncthreads();
    int q = tid & 3, r = tid >> 2;
    float acc[10];
    #pragma unroll
    for(int j = 0; j < 10; ++j) acc[j] = 0.f;
    #pragma unroll 4
    for(int k = 0; k < HDIM; ++k){
        float xv = xs[r][k];
        #pragma unroll
        for(int j = 0; j < 5; ++j){
            float2 w = *(const float2*)&ws[k][2 * q + 8 * j];
            acc[2*j+0] += xv * w.x;
            acc[2*j+1] += xv * w.y;
        }
    }
    int grow = row0 + r;
    if(grow < n){
        float dv = dinv[grow];
        #pragma unroll
        for(int j = 0; j < 5; ++j){
            float2 o; o.x = acc[2*j] * dv; o.y = acc[2*j+1] * dv;
            *(float2*)&h[(size_t)grow * ODIM + 2 * q + 8 * j] = o;
        }
    }
}

// ---------------- Aggregation (gather over CSR, rows pre-scaled by dinv[src]) ----------------
__global__ __launch_bounds__(256) void k_agg1(const float* __restrict__ h, const int* __restrict__ row_start,
                                              const int* __restrict__ esrc, const float* __restrict__ dinv,
                                              const float* __restrict__ bias, float* __restrict__ out, int n){
    int wid = (blockIdx.x * 256 + threadIdx.x) >> 6;
    int lane = threadIdx.x & 63;
    if(wid >= n) return;
    int c = lane * 2;
    float2 v = *(const float2*)&h[(size_t)wid * HDIM + c];
    float a0 = v.x, a1 = v.y;                      // self loop: h'[i]
    int e = row_start[wid], e1 = row_start[wid + 1];
    for(; e + 4 <= e1; e += 4){
        int s0 = esrc[e], s1 = esrc[e+1], s2 = esrc[e+2], s3 = esrc[e+3];
        float2 m0 = *(const float2*)&h[(size_t)s0 * HDIM + c];
        float2 m1 = *(const float2*)&h[(size_t)s1 * HDIM + c];
        float2 m2 = *(const float2*)&h[(size_t)s2 * HDIM + c];
        float2 m3 = *(const float2*)&h[(size_t)s3 * HDIM + c];
        a0 += (m0.x + m1.x) + (m2.x + m3.x);
        a1 += (m0.y + m1.y) + (m2.y + m3.y);
    }
    for(; e < e1; ++e){
        int s = esrc[e];
        float2 m = *(const float2*)&h[(size_t)s * HDIM + c];
        a0 += m.x; a1 += m.y;
    }
    float di = dinv[wid];
    float2 o;
    o.x = fmaxf(fmaf(a0, di, bias[c]),     0.f);
    o.y = fmaxf(fmaf(a1, di, bias[c + 1]), 0.f);
    *(float2*)&out[(size_t)wid * HDIM + c] = o;
}

__global__ __launch_bounds__(256) void k_agg2(const float* __restrict__ h, const int* __restrict__ row_start,
                                              const int* __restrict__ esrc, const float* __restrict__ dinv,
                                              const float* __restrict__ bias, float* __restrict__ out, int n){
    int wid = (blockIdx.x * 256 + threadIdx.x) >> 6;
    int lane = threadIdx.x & 63;
    if(wid >= n || lane >= ODIM) return;
    float a = h[(size_t)wid * ODIM + lane];        // self loop: h'[i]
    int e = row_start[wid], e1 = row_start[wid + 1];
    for(; e + 4 <= e1; e += 4){
        int s0 = esrc[e], s1 = esrc[e+1], s2 = esrc[e+2], s3 = esrc[e+3];
        float m0 = h[(size_t)s0 * ODIM + lane];
        float m1 = h[(size_t)s1 * ODIM + lane];
        float m2 = h[(size_t)s2 * ODIM + lane];
        float m3 = h[(size_t)s3 * ODIM + lane];
        a += (m0 + m1) + (m2 + m3);
    }
    for(; e < e1; ++e){
        int s = esrc[e];
        a += h[(size_t)s * ODIM + lane];
    }
    out[(size_t)wid * ODIM + lane] = fmaf(a, dinv[wid], bias[lane]);
}

extern "C" void kernel_launch(void* const* d_in, const int* in_sizes, int n_in,
                              void* d_out, int out_size, void* d_ws, size_t ws_size,
                              hipStream_t stream){
    const float* x  = (const float*)d_in[0];
    const int*   ei = (const int*)d_in[1];   // [2][E] int32
    const float* W1 = (const float*)d_in[2];
    const float* b1 = (const float*)d_in[3];
    const float* W2 = (const float*)d_in[4];
    const float* b2 = (const float*)d_in[5];
    float* out = (float*)d_out;

    const int n = NODES;
    const int E = in_sizes[1] / 2;
    const int* esrc_in = ei;
    const int* edst_in = ei + E;

    char* w = (char*)d_ws;
    int*   counts    = (int*)(w + (0u << 19));           // 400 KB
    int*   row_start = (int*)(w + (1u << 19));           // 400 KB (+1)
    int*   cursor    = (int*)(w + (2u << 19));           // 400 KB
    int*   partial   = (int*)(w + (3u << 19));           // 1 KB
    int*   pscan     = (int*)(w + (3u << 19) + 4096);    // 1 KB
    float* dinv      = (float*)(w + (4u << 19));         // 400 KB
    int*   esrc      = (int*)(w + (5u << 19));           // 6.4 MB (ends ~9.0 MB)
    unsigned short* wth = (unsigned short*)(w + (10u << 20));  // 64 KB  W1T hi
    unsigned short* wtl = (unsigned short*)(w + (11u << 20));  // 64 KB  W1T lo
    float* h1        = (float*)(w + (16u << 20));        // 51.2 MB  [N,128] (pre-scaled)
    float* h1r       = (float*)(w + (68u << 20));        // 51.2 MB  [N,128]
    float* h2        = h1;                                // reuse, 16 MB

    hipMemsetAsync(counts, 0, n * sizeof(int), stream);
    k_hist<<<(E + 255) / 256, 256, 0, stream>>>(edst_in, E, counts);
    k_psum<<<256, 256, 0, stream>>>(counts, partial, n);
    k_scan256<<<1, 256, 0, stream>>>(partial, pscan);
    k_scan_final<<<256, 512, 0, stream>>>(counts, pscan, n, E, row_start, cursor, dinv);
    k_fill<<<(E + 255) / 256, 256, 0, stream>>>(esrc_in, edst_in, E, cursor, esrc);
    k_wsplit<<<HDIM, INDIM, 0, stream>>>(W1, wth, wtl);

    k_gemm1<<<(NODES / 32 + 3) / 4, 256, 0, stream>>>(x, wth, wtl, dinv, h1, n);
    k_agg1<<<(n * 64 + 255) / 256, 256, 0, stream>>>(h1, row_start, esrc, dinv, b1, h1r, n);
    k_gemm2<<<(n + 63) / 64, 256, 0, stream>>>(h1r, W2, dinv, h2, n);
    k_agg2<<<(n * 64 + 255) / 256, 256, 0, stream>>>(h2, row_start, esrc, dinv, b2, out, n);
}